// Round 1
// baseline (591.519 us; speedup 1.0000x reference)
//
#include <hip/hip_runtime.h>

#define NN 64
#define KK 16

// Broadcast a float from a (wave-uniform) lane: v_readlane -> SGPR operand.
__device__ __forceinline__ float rlane(float v, int l) {
  return __int_as_float(__builtin_amdgcn_readlane(__float_as_int(v), l));
}

// One wave per batch. Lane i owns row i of the augmented complex system [A | b]
// in registers: Ar/Ai[64], Br/Bi[16]. Gauss-Jordan with partial pivoting.
//
// Rotation trick: each elimination step shifts the A-part left by one slot
// (folded into the update FMA), so the current pivot column is ALWAYS index 0
// -> all register indices are compile-time constants -> no scratch spills,
// and the k-loop body is k-independent (compact code, fits I-cache).
//
// Gauss-Jordan (eliminate in ALL rows except the current pivot row) means that
// after 64 steps each lane's row is d * e_s (s = step at which it was pivot),
// so x[s][c] = b[c] * (1/d) with no back-substitution phase.
__global__ void __launch_bounds__(64, 2)
cgj_solve(const float* __restrict__ A_r, const float* __restrict__ A_i,
          const float* __restrict__ b_r, const float* __restrict__ b_i,
          float* __restrict__ out, int nbatch) {
  const int batch = blockIdx.x;
  const int lane  = threadIdx.x;

  float Ar[NN], Ai[NN], Br[KK], Bi[KK];

  // ---- load: lane i reads its full row (float4-vectorized) ----
  const size_t abase = (size_t)batch * NN * NN + (size_t)lane * NN;
  const float4* pAr = reinterpret_cast<const float4*>(A_r + abase);
  const float4* pAi = reinterpret_cast<const float4*>(A_i + abase);
#pragma unroll
  for (int j = 0; j < NN / 4; ++j) {
    float4 v = pAr[j];
    Ar[4*j+0] = v.x; Ar[4*j+1] = v.y; Ar[4*j+2] = v.z; Ar[4*j+3] = v.w;
  }
#pragma unroll
  for (int j = 0; j < NN / 4; ++j) {
    float4 v = pAi[j];
    Ai[4*j+0] = v.x; Ai[4*j+1] = v.y; Ai[4*j+2] = v.z; Ai[4*j+3] = v.w;
  }
  const size_t bbase = (size_t)batch * NN * KK + (size_t)lane * KK;
  const float4* pbr = reinterpret_cast<const float4*>(b_r + bbase);
  const float4* pbi = reinterpret_cast<const float4*>(b_i + bbase);
#pragma unroll
  for (int j = 0; j < KK / 4; ++j) {
    float4 v = pbr[j];
    Br[4*j+0] = v.x; Br[4*j+1] = v.y; Br[4*j+2] = v.z; Br[4*j+3] = v.w;
  }
#pragma unroll
  for (int j = 0; j < KK / 4; ++j) {
    float4 v = pbi[j];
    Bi[4*j+0] = v.x; Bi[4*j+1] = v.y; Bi[4*j+2] = v.z; Bi[4*j+3] = v.w;
  }

  float invd_re = 0.f, invd_im = 0.f;
  int   mystep  = 0;
  bool  done    = false;

  for (int k = 0; k < NN; ++k) {
    // ---- partial pivot: argmax |r0|^2 over not-yet-chosen lanes ----
    float sc = done ? -1.0f : (Ar[0]*Ar[0] + Ai[0]*Ai[0]);
    int   bl = lane;
#pragma unroll
    for (int s = 32; s >= 1; s >>= 1) {
      float osc = __shfl_xor(sc, s);
      int   obl = __shfl_xor(bl, s);
      // total order (score desc, lane asc) -> associative max, all lanes agree
      if (osc > sc || (osc == sc && obl < bl)) { sc = osc; bl = obl; }
    }
    const int p = __builtin_amdgcn_readfirstlane(bl);

    // ---- pivot value and its complex reciprocal (uniform values) ----
    const float p_re = rlane(Ar[0], p);
    const float p_im = rlane(Ai[0], p);
    const float rd   = 1.0f / (p_re*p_re + p_im*p_im);
    const float ip_re =  p_re * rd;
    const float ip_im = -p_im * rd;

    // ---- per-lane multiplier m = r0 * inv(pivot); pivot row itself: m = 0 ----
    const float r0r = Ar[0], r0i = Ai[0];
    float m_re = r0r*ip_re - r0i*ip_im;
    float m_im = r0r*ip_im + r0i*ip_re;
    if (lane == p) {
      m_re = 0.f; m_im = 0.f;
      invd_re = ip_re; invd_im = ip_im;
      mystep = k; done = true;
    }

    // ---- A part: rotate-left-by-1 fused with elimination update ----
    // Live columns occupy positions [0 .. 63-k]; skip fully-dead 16-blocks
    // (wave-uniform branch). Slot 63 is dead after every step -> no wrap write.
#pragma unroll
    for (int blk = 0; blk < 4; ++blk) {
      if (63 - k >= 16 * blk) {
        const int j0 = (blk == 0) ? 1 : 16 * blk;
#pragma unroll
        for (int j = j0; j < 16 * (blk + 1); ++j) {
          const float sr = rlane(Ar[j], p);
          const float si = rlane(Ai[j], p);
          Ar[j-1] = Ar[j] - (m_re*sr - m_im*si);
          Ai[j-1] = Ai[j] - (m_re*si + m_im*sr);
        }
      }
    }

    // ---- b part (fixed positions, no rotation) ----
#pragma unroll
    for (int c = 0; c < KK; ++c) {
      const float sr = rlane(Br[c], p);
      const float si = rlane(Bi[c], p);
      Br[c] -= (m_re*sr - m_im*si);
      Bi[c] -= (m_re*si + m_im*sr);
    }
  }

  // ---- x[mystep][c] = b[c] * invd ; each lane writes its solution row ----
  float xr[KK], xi[KK];
#pragma unroll
  for (int c = 0; c < KK; ++c) {
    xr[c] = Br[c]*invd_re - Bi[c]*invd_im;
    xi[c] = Br[c]*invd_im + Bi[c]*invd_re;
  }
  const size_t obase = (size_t)batch * NN * KK + (size_t)mystep * KK;
  float* o_r = out + obase;
  float* o_i = out + (size_t)nbatch * NN * KK + obase;
#pragma unroll
  for (int j = 0; j < KK / 4; ++j) {
    float4 v;
    v.x = xr[4*j+0]; v.y = xr[4*j+1]; v.z = xr[4*j+2]; v.w = xr[4*j+3];
    reinterpret_cast<float4*>(o_r)[j] = v;
    float4 w;
    w.x = xi[4*j+0]; w.y = xi[4*j+1]; w.z = xi[4*j+2]; w.w = xi[4*j+3];
    reinterpret_cast<float4*>(o_i)[j] = w;
  }
}

extern "C" void kernel_launch(void* const* d_in, const int* in_sizes, int n_in,
                              void* d_out, int out_size, void* d_ws, size_t ws_size,
                              hipStream_t stream) {
  const float* A_r = (const float*)d_in[0];
  const float* A_i = (const float*)d_in[1];
  const float* b_r = (const float*)d_in[2];
  const float* b_i = (const float*)d_in[3];
  float* out = (float*)d_out;
  const int nbatch = in_sizes[0] / (NN * NN);  // 8192
  cgj_solve<<<nbatch, 64, 0, stream>>>(A_r, A_i, b_r, b_i, out, nbatch);
}

// Round 2
// 534.564 us; speedup vs baseline: 1.1065x; 1.1065x over previous
//
#include <hip/hip_runtime.h>

#define NN 64
#define KK 16

typedef float f32x2 __attribute__((ext_vector_type(2)));

// Broadcast a float from a (wave-uniform) lane: v_readlane -> SGPR operand.
__device__ __forceinline__ float rlane(float v, int l) {
  return __int_as_float(__builtin_amdgcn_readlane(__float_as_int(v), l));
}

// One wave per batch. Lane i owns row i of the augmented complex system [A | b]
// in registers as float2 {re,im}: C[64], Bv[16]. Gauss-Jordan with partial
// pivoting.
//
// Rotation trick: each elimination step shifts the A-part left by one slot
// (folded into the update FMA), so the current pivot column is ALWAYS index 0
// -> all register indices are compile-time constants.
//
// launch_bounds(64,1): give the compiler the full 512-reg unified budget so
// the ~175-float state is allocated in ARCH VGPRs. Round-1 evidence: with
// (64,2) the compiler put the arrays in AGPRs (VGPR_Count=96) and paid
// v_accvgpr_read/write on every access (~3x VALU inflation).
//
// float2 + elementwise_fma: lets the backend select v_pk_fma_f32 (packed f32,
// gfx90a+), halving the FMA stream for the complex rank-1 update.
__global__ void __launch_bounds__(64, 1)
cgj_solve(const float* __restrict__ A_r, const float* __restrict__ A_i,
          const float* __restrict__ b_r, const float* __restrict__ b_i,
          float* __restrict__ out, int nbatch) {
  const int batch = blockIdx.x;
  const int lane  = threadIdx.x;

  f32x2 C[NN];   // complex row of A
  f32x2 Bv[KK];  // complex row of b

  // ---- load: lane i reads its full row (float4-vectorized, planar->packed) ----
  const size_t abase = (size_t)batch * NN * NN + (size_t)lane * NN;
  const float4* pAr = reinterpret_cast<const float4*>(A_r + abase);
  const float4* pAi = reinterpret_cast<const float4*>(A_i + abase);
#pragma unroll
  for (int j = 0; j < NN / 4; ++j) {
    float4 vr = pAr[j];
    float4 vi = pAi[j];
    C[4*j+0] = f32x2{vr.x, vi.x};
    C[4*j+1] = f32x2{vr.y, vi.y};
    C[4*j+2] = f32x2{vr.z, vi.z};
    C[4*j+3] = f32x2{vr.w, vi.w};
  }
  const size_t bbase = (size_t)batch * NN * KK + (size_t)lane * KK;
  const float4* pbr = reinterpret_cast<const float4*>(b_r + bbase);
  const float4* pbi = reinterpret_cast<const float4*>(b_i + bbase);
#pragma unroll
  for (int j = 0; j < KK / 4; ++j) {
    float4 vr = pbr[j];
    float4 vi = pbi[j];
    Bv[4*j+0] = f32x2{vr.x, vi.x};
    Bv[4*j+1] = f32x2{vr.y, vi.y};
    Bv[4*j+2] = f32x2{vr.z, vi.z};
    Bv[4*j+3] = f32x2{vr.w, vi.w};
  }

  f32x2 invd = {0.f, 0.f};
  int   mystep = 0;
  bool  done   = false;

  for (int k = 0; k < NN; ++k) {
    // ---- partial pivot: argmax |C[0]|^2 over not-yet-chosen lanes ----
    float sc = done ? -1.0f : (C[0].x*C[0].x + C[0].y*C[0].y);
    int   bl = lane;
#pragma unroll
    for (int s = 32; s >= 1; s >>= 1) {
      float osc = __shfl_xor(sc, s);
      int   obl = __shfl_xor(bl, s);
      // total order (score desc, lane asc) -> associative, all lanes agree
      if (osc > sc || (osc == sc && obl < bl)) { sc = osc; bl = obl; }
    }
    const int p = __builtin_amdgcn_readfirstlane(bl);

    // ---- pivot value and its complex reciprocal (wave-uniform) ----
    const float p_re = rlane(C[0].x, p);
    const float p_im = rlane(C[0].y, p);
    const float rd   = 1.0f / (p_re*p_re + p_im*p_im);
    const float ip_re =  p_re * rd;
    const float ip_im = -p_im * rd;

    // ---- per-lane multiplier m = C[0] * inv(pivot); pivot row: m = 0 ----
    float m_re = C[0].x*ip_re - C[0].y*ip_im;
    float m_im = C[0].x*ip_im + C[0].y*ip_re;
    if (lane == p) {
      m_re = 0.f; m_im = 0.f;
      invd = f32x2{ip_re, ip_im};
      mystep = k; done = true;
    }
    const f32x2 mr2 = { -m_re, -m_re };  // per-lane, duplicated once per step
    const f32x2 mi2 = {  m_im,  m_im };

    // ---- A part: rotate-left-by-1 fused with elimination update ----
    // Live columns occupy slots [0 .. 63-k]; skip fully-dead 8-blocks
    // (wave-uniform branch).
#pragma unroll
    for (int blk = 0; blk < 8; ++blk) {
      if (63 - k >= 8 * blk) {
        const int j0 = (blk == 0) ? 1 : 8 * blk;
#pragma unroll
        for (int j = j0; j < 8 * (blk + 1); ++j) {
          const float sr = rlane(C[j].x, p);
          const float si = rlane(C[j].y, p);
          const f32x2 s1 = { sr, si };
          const f32x2 s2 = { si, -sr };
          f32x2 c = C[j];
          c = __builtin_elementwise_fma(mr2, s1, c);  // c += -m_re * {sr,si}
          c = __builtin_elementwise_fma(mi2, s2, c);  // c += +m_im * {si,-sr}
          C[j-1] = c;
        }
      }
    }

    // ---- b part (fixed positions, no rotation) ----
#pragma unroll
    for (int cc = 0; cc < KK; ++cc) {
      const float sr = rlane(Bv[cc].x, p);
      const float si = rlane(Bv[cc].y, p);
      const f32x2 s1 = { sr, si };
      const f32x2 s2 = { si, -sr };
      f32x2 c = Bv[cc];
      c = __builtin_elementwise_fma(mr2, s1, c);
      c = __builtin_elementwise_fma(mi2, s2, c);
      Bv[cc] = c;
    }
  }

  // ---- x[mystep][c] = Bv[c] * invd ; each lane writes its solution row ----
  float xr[KK], xi[KK];
#pragma unroll
  for (int cc = 0; cc < KK; ++cc) {
    xr[cc] = Bv[cc].x*invd.x - Bv[cc].y*invd.y;
    xi[cc] = Bv[cc].x*invd.y + Bv[cc].y*invd.x;
  }
  const size_t obase = (size_t)batch * NN * KK + (size_t)mystep * KK;
  float* o_r = out + obase;
  float* o_i = out + (size_t)nbatch * NN * KK + obase;
#pragma unroll
  for (int j = 0; j < KK / 4; ++j) {
    float4 v;
    v.x = xr[4*j+0]; v.y = xr[4*j+1]; v.z = xr[4*j+2]; v.w = xr[4*j+3];
    reinterpret_cast<float4*>(o_r)[j] = v;
    float4 w;
    w.x = xi[4*j+0]; w.y = xi[4*j+1]; w.z = xi[4*j+2]; w.w = xi[4*j+3];
    reinterpret_cast<float4*>(o_i)[j] = w;
  }
}

extern "C" void kernel_launch(void* const* d_in, const int* in_sizes, int n_in,
                              void* d_out, int out_size, void* d_ws, size_t ws_size,
                              hipStream_t stream) {
  const float* A_r = (const float*)d_in[0];
  const float* A_i = (const float*)d_in[1];
  const float* b_r = (const float*)d_in[2];
  const float* b_i = (const float*)d_in[3];
  float* out = (float*)d_out;
  const int nbatch = in_sizes[0] / (NN * NN);  // 8192
  cgj_solve<<<nbatch, 64, 0, stream>>>(A_r, A_i, b_r, b_i, out, nbatch);
}

// Round 3
// 398.278 us; speedup vs baseline: 1.4852x; 1.3422x over previous
//
#include <hip/hip_runtime.h>

#define NN 64
#define KK 16

// Broadcast a float from a (wave-uniform) lane: v_readlane -> SGPR operand.
__device__ __forceinline__ float rlane(float v, int l) {
  return __int_as_float(__builtin_amdgcn_readlane(__float_as_int(v), l));
}

// Wave64 argmax via DPP (VALU-rate, no LDS-pipe shuffles).
// key must be a u32 whose integer order matches the desired priority.
// Returns the max key over all 64 lanes (uniform via readlane 63).
__device__ __forceinline__ unsigned dpp_argmax64(unsigned key) {
  unsigned t;
  // row_shr:1,2,4,8 within each row of 16
  t = (unsigned)__builtin_amdgcn_update_dpp(0, (int)key, 0x111, 0xf, 0xf, true);
  key = key > t ? key : t;
  t = (unsigned)__builtin_amdgcn_update_dpp(0, (int)key, 0x112, 0xf, 0xf, true);
  key = key > t ? key : t;
  t = (unsigned)__builtin_amdgcn_update_dpp(0, (int)key, 0x114, 0xf, 0xf, true);
  key = key > t ? key : t;
  t = (unsigned)__builtin_amdgcn_update_dpp(0, (int)key, 0x118, 0xf, 0xf, true);
  key = key > t ? key : t;
  // row_bcast15: lane15 -> lanes 16..31, lane47 -> lanes 48..63
  t = (unsigned)__builtin_amdgcn_update_dpp(0, (int)key, 0x142, 0xf, 0xf, true);
  key = key > t ? key : t;
  // row_bcast31: lane31 -> lanes 32..63
  t = (unsigned)__builtin_amdgcn_update_dpp(0, (int)key, 0x143, 0xf, 0xf, true);
  key = key > t ? key : t;
  // global max now in lane 63
  return (unsigned)__builtin_amdgcn_readlane((int)key, 63);
}

// One wave per batch. Lane i owns row i of the augmented complex system [A | b]
// in registers: Cr/Ci[64], Br/Bi[16]. Gauss-Jordan with partial pivoting.
//
// Rotation trick: each elimination step shifts the A-part left by one slot
// (folded into the update FMA), so the current pivot column is ALWAYS index 0
// -> all register indices are compile-time constants.
//
// Pivot argmax is a DPP v_max_u32 chain (lane index packed into the low 6
// bits of the f32 score; order-preserving for non-negative floats) -- the
// round-2 profile showed the serial ds_swizzle shuffle chain stalling 43% of
// VALU issue slots.
//
// Update is scalar FMAs: per column 2 readlane + 4 v_fma_f32, each FMA one
// SGPR operand + free VOP3 neg modifiers (no vector operand marshalling).
__global__ void __launch_bounds__(64, 1)
cgj_solve(const float* __restrict__ A_r, const float* __restrict__ A_i,
          const float* __restrict__ b_r, const float* __restrict__ b_i,
          float* __restrict__ out, int nbatch) {
  const int batch = blockIdx.x;
  const int lane  = threadIdx.x;

  float Cr[NN], Ci[NN], Br[KK], Bi[KK];

  // ---- load: lane i reads its full row (float4-vectorized) ----
  const size_t abase = (size_t)batch * NN * NN + (size_t)lane * NN;
  const float4* pAr = reinterpret_cast<const float4*>(A_r + abase);
  const float4* pAi = reinterpret_cast<const float4*>(A_i + abase);
#pragma unroll
  for (int j = 0; j < NN / 4; ++j) {
    float4 v = pAr[j];
    Cr[4*j+0] = v.x; Cr[4*j+1] = v.y; Cr[4*j+2] = v.z; Cr[4*j+3] = v.w;
  }
#pragma unroll
  for (int j = 0; j < NN / 4; ++j) {
    float4 v = pAi[j];
    Ci[4*j+0] = v.x; Ci[4*j+1] = v.y; Ci[4*j+2] = v.z; Ci[4*j+3] = v.w;
  }
  const size_t bbase = (size_t)batch * NN * KK + (size_t)lane * KK;
  const float4* pbr = reinterpret_cast<const float4*>(b_r + bbase);
  const float4* pbi = reinterpret_cast<const float4*>(b_i + bbase);
#pragma unroll
  for (int j = 0; j < KK / 4; ++j) {
    float4 v = pbr[j];
    Br[4*j+0] = v.x; Br[4*j+1] = v.y; Br[4*j+2] = v.z; Br[4*j+3] = v.w;
  }
#pragma unroll
  for (int j = 0; j < KK / 4; ++j) {
    float4 v = pbi[j];
    Bi[4*j+0] = v.x; Bi[4*j+1] = v.y; Bi[4*j+2] = v.z; Bi[4*j+3] = v.w;
  }

  float invd_re = 0.f, invd_im = 0.f;
  int   mystep  = 0;
  bool  done    = false;

  for (int k = 0; k < NN; ++k) {
    // ---- partial pivot: DPP argmax of |C[0]|^2, lane idx in low 6 bits ----
    const float sc = Cr[0]*Cr[0] + Ci[0]*Ci[0];            // >= 0
    unsigned key = done ? (unsigned)lane
                        : ((__float_as_uint(sc) & ~63u) | (unsigned)lane);
    const unsigned kmax = dpp_argmax64(key);
    const int p = (int)(kmax & 63u);

    // ---- pivot value and its complex reciprocal (wave-uniform) ----
    const float p_re = rlane(Cr[0], p);
    const float p_im = rlane(Ci[0], p);
    const float d    = p_re*p_re + p_im*p_im;
    float rd = __builtin_amdgcn_rcpf(d);
    rd = rd * (2.0f - d * rd);                              // 1 Newton step
    const float ip_re =  p_re * rd;
    const float ip_im = -p_im * rd;

    // ---- per-lane multiplier m = C[0] * inv(pivot); pivot row: m = 0 ----
    float m_re = Cr[0]*ip_re - Ci[0]*ip_im;
    float m_im = Cr[0]*ip_im + Ci[0]*ip_re;
    if (lane == p) {
      m_re = 0.f; m_im = 0.f;
      invd_re = ip_re; invd_im = ip_im;
      mystep = k; done = true;
    }

    // ---- A part: rotate-left-by-1 fused with elimination update ----
    // Live columns occupy slots [0 .. 63-k]; skip fully-dead 8-blocks
    // (wave-uniform branch).
#pragma unroll
    for (int blk = 0; blk < 8; ++blk) {
      if (63 - k >= 8 * blk) {
        const int j0 = (blk == 0) ? 1 : 8 * blk;
#pragma unroll
        for (int j = j0; j < 8 * (blk + 1); ++j) {
          const float sr = rlane(Cr[j], p);
          const float si = rlane(Ci[j], p);
          // Cr' = Cr - m_re*sr + m_im*si ; Ci' = Ci - m_re*si - m_im*sr
          Cr[j-1] = __builtin_fmaf(-m_re, sr, __builtin_fmaf( m_im, si, Cr[j]));
          Ci[j-1] = __builtin_fmaf(-m_im, sr, __builtin_fmaf(-m_re, si, Ci[j]));
        }
      }
    }

    // ---- b part (fixed positions, no rotation) ----
#pragma unroll
    for (int c = 0; c < KK; ++c) {
      const float sr = rlane(Br[c], p);
      const float si = rlane(Bi[c], p);
      Br[c] = __builtin_fmaf(-m_re, sr, __builtin_fmaf( m_im, si, Br[c]));
      Bi[c] = __builtin_fmaf(-m_im, sr, __builtin_fmaf(-m_re, si, Bi[c]));
    }
  }

  // ---- x[mystep][c] = b[c] * invd ; each lane writes its solution row ----
  float xr[KK], xi[KK];
#pragma unroll
  for (int c = 0; c < KK; ++c) {
    xr[c] = Br[c]*invd_re - Bi[c]*invd_im;
    xi[c] = Br[c]*invd_im + Bi[c]*invd_re;
  }
  const size_t obase = (size_t)batch * NN * KK + (size_t)mystep * KK;
  float* o_r = out + obase;
  float* o_i = out + (size_t)nbatch * NN * KK + obase;
#pragma unroll
  for (int j = 0; j < KK / 4; ++j) {
    float4 v;
    v.x = xr[4*j+0]; v.y = xr[4*j+1]; v.z = xr[4*j+2]; v.w = xr[4*j+3];
    reinterpret_cast<float4*>(o_r)[j] = v;
    float4 w;
    w.x = xi[4*j+0]; w.y = xi[4*j+1]; w.z = xi[4*j+2]; w.w = xi[4*j+3];
    reinterpret_cast<float4*>(o_i)[j] = w;
  }
}

extern "C" void kernel_launch(void* const* d_in, const int* in_sizes, int n_in,
                              void* d_out, int out_size, void* d_ws, size_t ws_size,
                              hipStream_t stream) {
  const float* A_r = (const float*)d_in[0];
  const float* A_i = (const float*)d_in[1];
  const float* b_r = (const float*)d_in[2];
  const float* b_i = (const float*)d_in[3];
  float* out = (float*)d_out;
  const int nbatch = in_sizes[0] / (NN * NN);  // 8192
  cgj_solve<<<nbatch, 64, 0, stream>>>(A_r, A_i, b_r, b_i, out, nbatch);
}